// Round 7
// baseline (171.608 us; speedup 1.0000x reference)
//
#include <hip/hip_runtime.h>
#include <hip/hip_bf16.h>
#include <cstdint>
#include <cstddef>

// Problem dims (fixed by the reference)
#define NEXP   8
#define BATCH  8
#define NTOK   2048
#define DDIM   512
#define DFFDIM 2048
#define DCOND  512

typedef float  f32x4  __attribute__((ext_vector_type(4)));
typedef __bf16 bf16x8 __attribute__((ext_vector_type(8)));

using as1_cvoid = __attribute__((address_space(1))) const void;
using as3_void  = __attribute__((address_space(3))) void;

__device__ __forceinline__ void async_copy16(const void* g, void* l) {
  __builtin_amdgcn_global_load_lds((as1_cvoid*)g, (as3_void*)l, 16, 0, 0);
}

__device__ __forceinline__ unsigned short f2bf_bits(float f) {
  __hip_bfloat16 h = __float2bfloat16(f);
  return *reinterpret_cast<unsigned short*>(&h);
}

// fast tanh-approx gelu: 0.5v(1+tanh(z)) == v * sigmoid(2z)
__device__ __forceinline__ float gelu_fast(float v) {
  float y = v * fmaf(0.0713548162726f, v * v, 1.5957691216057f);
  float e = exp2f(-1.44269504089f * y);
  return v * __builtin_amdgcn_rcpf(1.0f + e);
}

// ---------------------------------------------------------------------------
// 1) scale/shift = cond[b] @ W_cond[route[b]] + b_cond[route[b]] -> ss[B][1024]
// ---------------------------------------------------------------------------
__global__ void mod_kernel(const float* __restrict__ cond,
                           const int* __restrict__ route,
                           const float* __restrict__ W_cond,
                           const float* __restrict__ b_cond,
                           float* __restrict__ ss) {
  const int b = blockIdx.y;
  const int m = route[b];
  const int tj = threadIdx.x & 63;
  const int cq = threadIdx.x >> 6;            // 0..3
  const int j = blockIdx.x * 64 + tj;
  const float* wc = W_cond + (size_t)m * DCOND * (2 * DDIM);
  const float* cb = cond + (size_t)b * DCOND;
  float acc = 0.f;
#pragma unroll 4
  for (int c = cq * 128; c < cq * 128 + 128; ++c)
    acc += cb[c] * wc[(size_t)c * (2 * DDIM) + j];
  __shared__ float red[4][64];
  red[cq][tj] = acc;
  __syncthreads();
  if (cq == 0) {
    float v = red[0][tj] + red[1][tj] + red[2][tj] + red[3][tj];
    ss[(size_t)b * (2 * DDIM) + j] = v + b_cond[(size_t)m * (2 * DDIM) + j];
  }
}

// ---------------------------------------------------------------------------
// 2) x_mod = bf16( x * (1+scale) + shift )   [B][N][D] bf16
// ---------------------------------------------------------------------------
__global__ void film_kernel(const float* __restrict__ x,
                            const float* __restrict__ ss,
                            __hip_bfloat16* __restrict__ xmod) {
  const size_t idx = (size_t)blockIdx.x * blockDim.x + threadIdx.x;
  const int d4 = (int)(idx & (DDIM / 4 - 1));
  const int b  = (int)(idx >> 18);
  const float4 xv = reinterpret_cast<const float4*>(x)[idx];
  const float4 sc = reinterpret_cast<const float4*>(ss + (size_t)b * 1024)[d4];
  const float4 sh = reinterpret_cast<const float4*>(ss + (size_t)b * 1024 + DDIM)[d4];
  float r0 = xv.x * (1.f + sc.x) + sh.x;
  float r1 = xv.y * (1.f + sc.y) + sh.y;
  float r2 = xv.z * (1.f + sc.z) + sh.z;
  float r3 = xv.w * (1.f + sc.w) + sh.w;
  ushort4 ov;
  ov.x = f2bf_bits(r0); ov.y = f2bf_bits(r1);
  ov.z = f2bf_bits(r2); ov.w = f2bf_bits(r3);
  reinterpret_cast<ushort4*>(xmod)[idx] = ov;
}

// ---------------------------------------------------------------------------
// 3) transpose + f32->bf16:  in [M][L][R] f32  ->  out [M][R][L] bf16
// ---------------------------------------------------------------------------
__global__ void transpose_cvt(const float* __restrict__ in,
                              __hip_bfloat16* __restrict__ outp,
                              int L, int R,
                              const int* __restrict__ route) {
  const int mi = blockIdx.z;
  bool used = false;
#pragma unroll
  for (int b = 0; b < BATCH; ++b) used |= (route[b] == mi);
  if (!used) return;

  __shared__ float tile[32][33];
  const float* inm = in + (size_t)mi * L * R;
  __hip_bfloat16* outm = outp + (size_t)mi * L * R;
  const int r0 = blockIdx.x * 32, l0 = blockIdx.y * 32;
  const int tx = threadIdx.x, ty = threadIdx.y;
#pragma unroll
  for (int i = 0; i < 32; i += 8)
    tile[ty + i][tx] = inm[(size_t)(l0 + ty + i) * R + r0 + tx];
  __syncthreads();
#pragma unroll
  for (int i = 0; i < 32; i += 8)
    outm[(size_t)(r0 + ty + i) * L + l0 + tx] = __float2bfloat16(tile[tx][ty + i]);
}

// ---------------------------------------------------------------------------
// 4a) WIDE GEMM (GEMM1): BM=256, BN=128, BK=32, 256 threads = 4 waves (2Mx2N),
//     wave-tile 128x64 (acc 8x4).  LDS 48KB (2-slot dbuf) -> 3 blocks/CU =
//     12 waves/CU.  LDS bytes/MFMA: 375 read + 187 write = 2.2 cyc vs 1.2 cyc
//     MFMA issue -> MfmaUtil cap ~55% (vs 40% at 64x64 wave-tile).
//     Swizzle (64B rows, 4 chunks): LDS(r,c) holds global(r, c ^ S(r)),
//     S(r) = (r&3)^((r>>2)&3); read chunk = lq ^ S(lrow) (pure lane fn);
//     worst-case 2-way bank aliasing (free).  Counted vmcnt(6) depth-1,
//     two raw barriers per tile (R6-proven skeleton).
// ---------------------------------------------------------------------------
template <int EPI>
__global__ __launch_bounds__(256) void gemm_wide(
    const __hip_bfloat16* __restrict__ Abase,
    const __hip_bfloat16* __restrict__ Btbase,
    const float* __restrict__ biasbase,
    void* __restrict__ outbase,
    const int* __restrict__ route,
    int Mdim, int Ndim, int Kdim, int tilesX) {
  const int bid  = blockIdx.x;
  const int b    = bid & 7;            // batch -> XCD
  const int tile = bid >> 3;
  const int bx   = tile % tilesX;      // M-tile (256-wide)
  const int by   = tile / tilesX;      // N-tile (128-wide)
  const int m = route[b];
  const __hip_bfloat16* A  = Abase  + (size_t)b * Mdim * Kdim;
  const __hip_bfloat16* Bt = Btbase + (size_t)m * Ndim * Kdim;
  const float* bias = biasbase + (size_t)m * Ndim;
  const int r0 = bx * 256;
  const int n0 = by * 128;

  __shared__ alignas(16) __hip_bfloat16 As[2][256 * 32];   // 32 KB
  __shared__ alignas(16) __hip_bfloat16 Bs[2][128 * 32];   // 16 KB

  const int t = threadIdx.x;
  const int w = t >> 6, l = t & 63;
  const int wm = w >> 1, wn = w & 1;   // 2x2 waves, wave-tile 128x64

  // staging: chunk c_lin = i*256 + t -> row i*64 + (t>>2), chunk t&3.
  // source global chunk = (t&3) ^ S(row), S periodic-16 in row.
  const int srow = t >> 2;                                   // 0..63
  const int scol = (t & 3) ^ ((t >> 2) & 3) ^ ((t >> 4) & 3);

#define STAGE(s_, k0)                                                          \
  { _Pragma("unroll")                                                          \
    for (int i = 0; i < 4; ++i)                                                \
      async_copy16(A + (size_t)(r0 + i * 64 + srow) * Kdim + (k0) + scol * 8,  \
                   &As[s_][(i * 256 + t) * 8]);                                \
    _Pragma("unroll")                                                          \
    for (int i = 0; i < 2; ++i)                                                \
      async_copy16(Bt + (size_t)(n0 + i * 64 + srow) * Kdim + (k0) + scol * 8, \
                   &Bs[s_][(i * 256 + t) * 8]); }

  // ds_read: frag row = base + lrow; chunk = lq ^ S(lrow)  (base ≡ 0 mod 16)
  const int lrow = l & 15, lq = l >> 4;
  const int kx = lq ^ (lrow & 3) ^ ((lrow >> 2) & 3);

  f32x4 acc[8][4] = {};
  const int nt = Kdim >> 5;            // K-tiles of 32

  STAGE(0, 0)                          // prologue

  for (int kt = 0; kt < nt; ++kt) {
    const int s = kt & 1;
    if (kt + 1 < nt) {
      STAGE(s ^ 1, (kt + 1) * 32)
      asm volatile("s_waitcnt vmcnt(6)" ::: "memory");   // tile kt's 6 done
    } else {
      asm volatile("s_waitcnt vmcnt(0)" ::: "memory");
    }
    __builtin_amdgcn_s_barrier();
    __builtin_amdgcn_sched_barrier(0);

    const __hip_bfloat16* as_ = As[s];
    const __hip_bfloat16* bs_ = Bs[s];
    bf16x8 af[8], bfr[4];
#pragma unroll
    for (int nb = 0; nb < 4; ++nb)
      bfr[nb] = *reinterpret_cast<const bf16x8*>(
          &bs_[((wn * 64 + nb * 16 + lrow) * 4 + kx) * 8]);
#pragma unroll
    for (int mb = 0; mb < 8; ++mb)
      af[mb] = *reinterpret_cast<const bf16x8*>(
          &as_[((wm * 128 + mb * 16 + lrow) * 4 + kx) * 8]);
#pragma unroll
    for (int mb = 0; mb < 8; ++mb)
#pragma unroll
      for (int nb = 0; nb < 4; ++nb)
        acc[mb][nb] = __builtin_amdgcn_mfma_f32_16x16x32_bf16(
            af[mb], bfr[nb], acc[mb][nb], 0, 0, 0);

    __builtin_amdgcn_sched_barrier(0);
    __builtin_amdgcn_s_barrier();      // reads of slot s done
  }
#undef STAGE

  // ---- epilogue: C/D layout col=lane&15, row=(lane>>4)*4+j ----
  if (EPI == 0) {
    __hip_bfloat16* out = (__hip_bfloat16*)outbase + (size_t)b * Mdim * Ndim;
#pragma unroll
    for (int mb = 0; mb < 8; ++mb) {
      const int row = r0 + wm * 128 + mb * 16 + lq * 4;
#pragma unroll
      for (int nb = 0; nb < 4; ++nb) {
        const int col = n0 + wn * 64 + nb * 16 + lrow;
        const float bv = bias[col];
#pragma unroll
        for (int j = 0; j < 4; ++j) {
          float g = gelu_fast(acc[mb][nb][j] + bv);
          out[(size_t)(row + j) * Ndim + col] = __float2bfloat16(g);
        }
      }
    }
  } else {
    float* out = (float*)outbase + (size_t)b * Mdim * Ndim;
#pragma unroll
    for (int mb = 0; mb < 8; ++mb) {
      const int row = r0 + wm * 128 + mb * 16 + lq * 4;
#pragma unroll
      for (int nb = 0; nb < 4; ++nb) {
        const int col = n0 + wn * 64 + nb * 16 + lrow;
        const float bv = bias[col];
#pragma unroll
        for (int j = 0; j < 4; ++j)
          out[(size_t)(row + j) * Ndim + col] = acc[mb][nb][j] + bv;
      }
    }
  }
}

// ---------------------------------------------------------------------------
// 4b) GEMM2 kernel — R6's proven gemm_db2 (BM=BN=128, BK=64), unchanged.
// ---------------------------------------------------------------------------
template <int EPI>
__global__ __launch_bounds__(256, 2) void gemm_db2(
    const __hip_bfloat16* __restrict__ Abase,
    const __hip_bfloat16* __restrict__ Btbase,
    const float* __restrict__ biasbase,
    void* __restrict__ outbase,
    const int* __restrict__ route,
    int Mdim, int Ndim, int Kdim, int tilesX) {
  const int bid  = blockIdx.x;
  const int b    = bid & 7;
  const int tile = bid >> 3;
  const int bx   = tile % tilesX;
  const int by   = tile / tilesX;
  const int m = route[b];
  const __hip_bfloat16* A  = Abase  + (size_t)b * Mdim * Kdim;
  const __hip_bfloat16* Bt = Btbase + (size_t)m * Ndim * Kdim;
  const float* bias = biasbase + (size_t)m * Ndim;
  const int r0 = bx * 128;
  const int n0 = by * 128;

  __shared__ alignas(16) __hip_bfloat16 As[2][128 * 64];
  __shared__ alignas(16) __hip_bfloat16 Bs[2][128 * 64];

  const int t = threadIdx.x;
  const int w = t >> 6, l = t & 63;
  const int wr = w >> 1, wc = w & 1;

  const int srow = t >> 3;
  const int scol = (t & 7) ^ ((t >> 3) & 7);

#define STAGE(s_, k0)                                                         \
  { _Pragma("unroll")                                                         \
    for (int i = 0; i < 4; ++i)                                               \
      async_copy16(A + (size_t)(r0 + i * 32 + srow) * Kdim + (k0) + scol * 8, \
                   &As[s_][(i * 256 + t) * 8]);                               \
    _Pragma("unroll")                                                         \
    for (int i = 0; i < 4; ++i)                                               \
      async_copy16(Bt + (size_t)(n0 + i * 32 + srow) * Kdim + (k0) + scol * 8,\
                   &Bs[s_][(i * 256 + t) * 8]); }

  const int lrow = l & 15, lq = l >> 4, lx = l & 7;
  f32x4 acc[4][4] = {};
  const int nt = Kdim >> 6;

  STAGE(0, 0)

  for (int kt = 0; kt < nt; ++kt) {
    const int s = kt & 1;
    if (kt + 1 < nt) {
      STAGE(s ^ 1, (kt + 1) * 64)
      asm volatile("s_waitcnt vmcnt(8)" ::: "memory");
    } else {
      asm volatile("s_waitcnt vmcnt(0)" ::: "memory");
    }
    __builtin_amdgcn_s_barrier();
    __builtin_amdgcn_sched_barrier(0);

    const __hip_bfloat16* as_ = As[s];
    const __hip_bfloat16* bs_ = Bs[s];
    bf16x8 af[4][2], bfr[4][2];
#pragma unroll
    for (int mb = 0; mb < 4; ++mb) {
      const int row = wr * 64 + mb * 16 + lrow;
      af[mb][0] = *reinterpret_cast<const bf16x8*>(&as_[(row * 8 + ((0 + lq) ^ lx)) * 8]);
      af[mb][1] = *reinterpret_cast<const bf16x8*>(&as_[(row * 8 + ((4 + lq) ^ lx)) * 8]);
    }
#pragma unroll
    for (int nb = 0; nb < 4; ++nb) {
      const int row = wc * 64 + nb * 16 + lrow;
      bfr[nb][0] = *reinterpret_cast<const bf16x8*>(&bs_[(row * 8 + ((0 + lq) ^ lx)) * 8]);
      bfr[nb][1] = *reinterpret_cast<const bf16x8*>(&bs_[(row * 8 + ((4 + lq) ^ lx)) * 8]);
    }
#pragma unroll
    for (int mb = 0; mb < 4; ++mb)
#pragma unroll
      for (int nb = 0; nb < 4; ++nb) {
        acc[mb][nb] = __builtin_amdgcn_mfma_f32_16x16x32_bf16(
            af[mb][0], bfr[nb][0], acc[mb][nb], 0, 0, 0);
        acc[mb][nb] = __builtin_amdgcn_mfma_f32_16x16x32_bf16(
            af[mb][1], bfr[nb][1], acc[mb][nb], 0, 0, 0);
      }

    __builtin_amdgcn_sched_barrier(0);
    __builtin_amdgcn_s_barrier();
  }
#undef STAGE

  if (EPI == 0) {
    __hip_bfloat16* out = (__hip_bfloat16*)outbase + (size_t)b * Mdim * Ndim;
#pragma unroll
    for (int mb = 0; mb < 4; ++mb) {
      const int row = r0 + wr * 64 + mb * 16 + lq * 4;
#pragma unroll
      for (int nb = 0; nb < 4; ++nb) {
        const int col = n0 + wc * 64 + nb * 16 + lrow;
        const float bv = bias[col];
#pragma unroll
        for (int j = 0; j < 4; ++j) {
          float g = gelu_fast(acc[mb][nb][j] + bv);
          out[(size_t)(row + j) * Ndim + col] = __float2bfloat16(g);
        }
      }
    }
  } else {
    float* out = (float*)outbase + (size_t)b * Mdim * Ndim;
#pragma unroll
    for (int mb = 0; mb < 4; ++mb) {
      const int row = r0 + wr * 64 + mb * 16 + lq * 4;
#pragma unroll
      for (int nb = 0; nb < 4; ++nb) {
        const int col = n0 + wc * 64 + nb * 16 + lrow;
        const float bv = bias[col];
#pragma unroll
        for (int j = 0; j < 4; ++j)
          out[(size_t)(row + j) * Ndim + col] = acc[mb][nb][j] + bv;
      }
    }
  }
}

// ---------------------------------------------------------------------------
extern "C" void kernel_launch(void* const* d_in, const int* in_sizes, int n_in,
                              void* d_out, int out_size, void* d_ws, size_t ws_size,
                              hipStream_t stream) {
  const float* x      = (const float*)d_in[0];
  const float* cond   = (const float*)d_in[1];
  const int*   route  = (const int*)d_in[2];
  const float* W_cond = (const float*)d_in[3];
  const float* b_cond = (const float*)d_in[4];
  const float* W1     = (const float*)d_in[5];
  const float* b1     = (const float*)d_in[6];
  const float* W2     = (const float*)d_in[7];
  const float* b2     = (const float*)d_in[8];
  float* out = (float*)d_out;

  // workspace layout (bytes)
  const size_t SS_OFF   = 0;
  const size_t XMOD_OFF = 32768;
  const size_t W1T_OFF  = XMOD_OFF + (size_t)BATCH * NTOK * DDIM * 2;
  const size_t W2T_OFF  = W1T_OFF + (size_t)NEXP * DDIM * DFFDIM * 2;
  const size_t H_OFF    = W2T_OFF + (size_t)NEXP * DFFDIM * DDIM * 2;
  const size_t NEED     = H_OFF + (size_t)BATCH * NTOK * DFFDIM * 2;
  if (ws_size < NEED) return;

  char* ws = (char*)d_ws;
  float* ss            = (float*)(ws + SS_OFF);
  __hip_bfloat16* xmod = (__hip_bfloat16*)(ws + XMOD_OFF);
  __hip_bfloat16* w1t  = (__hip_bfloat16*)(ws + W1T_OFF);
  __hip_bfloat16* w2t  = (__hip_bfloat16*)(ws + W2T_OFF);
  __hip_bfloat16* h    = (__hip_bfloat16*)(ws + H_OFF);

  // 1) cond modulation
  mod_kernel<<<dim3(2 * DDIM / 64, BATCH), 256, 0, stream>>>(cond, route, W_cond, b_cond, ss);

  // 2) FiLM -> bf16
  {
    const size_t groups = (size_t)BATCH * NTOK * DDIM / 4;
    film_kernel<<<(unsigned)(groups / 256), 256, 0, stream>>>(x, ss, xmod);
  }

  // 3) weight transpose+convert (routed experts only)
  transpose_cvt<<<dim3(DFFDIM / 32, DDIM / 32, NEXP), dim3(32, 8), 0, stream>>>(W1, w1t, DDIM, DFFDIM, route);
  transpose_cvt<<<dim3(DDIM / 32, DFFDIM / 32, NEXP), dim3(32, 8), 0, stream>>>(W2, w2t, DFFDIM, DDIM, route);

  // 4) GEMM1: h = gelu(xmod @ W1 + b1)   grid 8*16*8 = 1024 blocks
  gemm_wide<0><<<(NTOK / 256) * (DFFDIM / 128) * BATCH, 256, 0, stream>>>(
      xmod, w1t, b1, h, route, NTOK, DFFDIM, DDIM, NTOK / 256);

  // 5) GEMM2: out = h @ W2 + b2          grid 16*4*8 = 512 blocks
  gemm_db2<1><<<(NTOK / 128) * (DDIM / 128) * BATCH, 256, 0, stream>>>(
      h, w2t, b2, out, route, NTOK, DDIM, DFFDIM, NTOK / 128);
}

// Round 8
// 163.726 us; speedup vs baseline: 1.0481x; 1.0481x over previous
//
#include <hip/hip_runtime.h>
#include <hip/hip_bf16.h>
#include <cstdint>
#include <cstddef>

// Problem dims (fixed by the reference)
#define NEXP   8
#define BATCH  8
#define NTOK   2048
#define DDIM   512
#define DFFDIM 2048
#define DCOND  512

typedef float  f32x4  __attribute__((ext_vector_type(4)));
typedef __bf16 bf16x8 __attribute__((ext_vector_type(8)));

using as1_cvoid = __attribute__((address_space(1))) const void;
using as3_void  = __attribute__((address_space(3))) void;

__device__ __forceinline__ void async_copy16(const void* g, void* l) {
  __builtin_amdgcn_global_load_lds((as1_cvoid*)g, (as3_void*)l, 16, 0, 0);
}

__device__ __forceinline__ unsigned short f2bf_bits(float f) {
  __hip_bfloat16 h = __float2bfloat16(f);
  return *reinterpret_cast<unsigned short*>(&h);
}

// fast tanh-approx gelu: 0.5v(1+tanh(z)) == v * sigmoid(2z)
__device__ __forceinline__ float gelu_fast(float v) {
  float y = v * fmaf(0.0713548162726f, v * v, 1.5957691216057f);
  float e = exp2f(-1.44269504089f * y);
  return v * __builtin_amdgcn_rcpf(1.0f + e);
}

// ---------------------------------------------------------------------------
// 1) scale/shift = cond[b] @ W_cond[route[b]] + b_cond[route[b]] -> ss[B][1024]
// ---------------------------------------------------------------------------
__global__ void mod_kernel(const float* __restrict__ cond,
                           const int* __restrict__ route,
                           const float* __restrict__ W_cond,
                           const float* __restrict__ b_cond,
                           float* __restrict__ ss) {
  const int b = blockIdx.y;
  const int m = route[b];
  const int tj = threadIdx.x & 63;
  const int cq = threadIdx.x >> 6;            // 0..3
  const int j = blockIdx.x * 64 + tj;
  const float* wc = W_cond + (size_t)m * DCOND * (2 * DDIM);
  const float* cb = cond + (size_t)b * DCOND;
  float acc = 0.f;
#pragma unroll 4
  for (int c = cq * 128; c < cq * 128 + 128; ++c)
    acc += cb[c] * wc[(size_t)c * (2 * DDIM) + j];
  __shared__ float red[4][64];
  red[cq][tj] = acc;
  __syncthreads();
  if (cq == 0) {
    float v = red[0][tj] + red[1][tj] + red[2][tj] + red[3][tj];
    ss[(size_t)b * (2 * DDIM) + j] = v + b_cond[(size_t)m * (2 * DDIM) + j];
  }
}

// ---------------------------------------------------------------------------
// 2) x_mod = bf16( x * (1+scale) + shift )   [B][N][D] bf16
// ---------------------------------------------------------------------------
__global__ void film_kernel(const float* __restrict__ x,
                            const float* __restrict__ ss,
                            __hip_bfloat16* __restrict__ xmod) {
  const size_t idx = (size_t)blockIdx.x * blockDim.x + threadIdx.x;
  const int d4 = (int)(idx & (DDIM / 4 - 1));
  const int b  = (int)(idx >> 18);
  const float4 xv = reinterpret_cast<const float4*>(x)[idx];
  const float4 sc = reinterpret_cast<const float4*>(ss + (size_t)b * 1024)[d4];
  const float4 sh = reinterpret_cast<const float4*>(ss + (size_t)b * 1024 + DDIM)[d4];
  float r0 = xv.x * (1.f + sc.x) + sh.x;
  float r1 = xv.y * (1.f + sc.y) + sh.y;
  float r2 = xv.z * (1.f + sc.z) + sh.z;
  float r3 = xv.w * (1.f + sc.w) + sh.w;
  ushort4 ov;
  ov.x = f2bf_bits(r0); ov.y = f2bf_bits(r1);
  ov.z = f2bf_bits(r2); ov.w = f2bf_bits(r3);
  reinterpret_cast<ushort4*>(xmod)[idx] = ov;
}

// ---------------------------------------------------------------------------
// 3) transpose + f32->bf16:  in [M][L][R] f32  ->  out [M][R][L] bf16
// ---------------------------------------------------------------------------
__global__ void transpose_cvt(const float* __restrict__ in,
                              __hip_bfloat16* __restrict__ outp,
                              int L, int R,
                              const int* __restrict__ route) {
  const int mi = blockIdx.z;
  bool used = false;
#pragma unroll
  for (int b = 0; b < BATCH; ++b) used |= (route[b] == mi);
  if (!used) return;

  __shared__ float tile[32][33];
  const float* inm = in + (size_t)mi * L * R;
  __hip_bfloat16* outm = outp + (size_t)mi * L * R;
  const int r0 = blockIdx.x * 32, l0 = blockIdx.y * 32;
  const int tx = threadIdx.x, ty = threadIdx.y;
#pragma unroll
  for (int i = 0; i < 32; i += 8)
    tile[ty + i][tx] = inm[(size_t)(l0 + ty + i) * R + r0 + tx];
  __syncthreads();
#pragma unroll
  for (int i = 0; i < 32; i += 8)
    outm[(size_t)(r0 + ty + i) * L + l0 + tx] = __float2bfloat16(tile[tx][ty + i]);
}

// B-fragment direct load: global (L2-resident expert weights) -> regs.
// dst[nb][kk] = 8 bf16 at row (bn0 + nb*16 + lrow), k = kt*64 + kk*32 + lq*8
__device__ __forceinline__ void loadB(bf16x8 (&dst)[4][2],
                                      const __hip_bfloat16* __restrict__ Bt,
                                      int bn0, int Kdim, int kt,
                                      int lrow, int lq) {
#pragma unroll
  for (int nb = 0; nb < 4; ++nb)
#pragma unroll
    for (int kk = 0; kk < 2; ++kk)
      dst[nb][kk] = *reinterpret_cast<const bf16x8*>(
          &Bt[(size_t)(bn0 + nb * 16 + lrow) * Kdim + kt * 64 + kk * 32 + lq * 8]);
}

// ---------------------------------------------------------------------------
// 4a) GEMM1: B-direct variant.  BM=BN=128, BK=64, 256 threads (4 waves 2x2,
//     wave-tile 64x64).  A (xmod) in LDS: 2-slot dbuf, 32KB, R6-verified
//     swizzle (linear gload_lds dest + inverse-swizzled src + swizzled read).
//     B (expert weights, ~2MB/expert, L2-resident per-XCD via batch->XCD
//     grid mapping) read DIRECTLY global->reg, explicit even/odd reg double
//     buffer, one tile of prefetch lead.  Halves LDS traffic vs R6
//     (1024->512 cyc/tile < 621 cyc MFMA -> LDS pipe unbinds).
//     Ledger: newest 12 outstanding at the wait = A(t+1) 4 gload_lds +
//     B(t+1) 8 reg loads -> vmcnt(12) retires A(t) and B(t).
//     Two raw barriers per tile (R6 skeleton): entry = A(t) visible
//     block-wide; trailing = slot-s reads done -> next stage may overwrite.
// ---------------------------------------------------------------------------
template <int EPI>
__global__ __launch_bounds__(256) void gemm_bd(
    const __hip_bfloat16* __restrict__ Abase,
    const __hip_bfloat16* __restrict__ Btbase,
    const float* __restrict__ biasbase,
    void* __restrict__ outbase,
    const int* __restrict__ route,
    int Mdim, int Ndim, int Kdim, int tilesX) {
  const int bid  = blockIdx.x;
  const int b    = bid & 7;            // batch -> XCD (B weights L2-resident)
  const int tile = bid >> 3;
  const int bx   = tile % tilesX;
  const int by   = tile / tilesX;
  const int m = route[b];
  const __hip_bfloat16* A  = Abase  + (size_t)b * Mdim * Kdim;
  const __hip_bfloat16* Bt = Btbase + (size_t)m * Ndim * Kdim;
  const float* bias = biasbase + (size_t)m * Ndim;
  const int r0 = bx * 128;
  const int n0 = by * 128;

  __shared__ alignas(16) __hip_bfloat16 As[2][128 * 64];   // 32 KB total

  const int t = threadIdx.x;
  const int w = t >> 6, l = t & 63;
  const int wr = w >> 1, wc = w & 1;   // 2x2 waves, wave-tile 64x64

  // A staging (verbatim R6): linear dest, inverse-swizzled source chunk
  const int srow = t >> 3;                     // 0..31
  const int scol = (t & 7) ^ ((t >> 3) & 7);   // 16B chunk in row

#define STAGE_A(s_, k0)                                                       \
  { _Pragma("unroll")                                                         \
    for (int i = 0; i < 4; ++i)                                               \
      async_copy16(A + (size_t)(r0 + i * 32 + srow) * Kdim + (k0) + scol * 8, \
                   &As[s_][(i * 256 + t) * 8]); }

  const int lrow = l & 15, lq = l >> 4, lx = l & 7;
  const int bn0 = n0 + wc * 64;
  f32x4 acc[4][4] = {};
  const int nt = Kdim >> 6;            // even (8 or 32)

  bf16x8 bE[4][2], bO[4][2];           // even/odd tile B-frag buffers

  // prologue: tile 0 -> slot 0 (LDS) + B(0) -> bE (regs)
  STAGE_A(0, 0)
  loadB(bE, Bt, bn0, Kdim, 0, lrow, lq);

#define BODY(t_, s_, bCur, bNxt)                                              \
  {                                                                           \
    if ((t_) + 1 < nt) {                                                      \
      STAGE_A((s_) ^ 1, ((t_) + 1) * 64)                                      \
      loadB(bNxt, Bt, bn0, Kdim, (t_) + 1, lrow, lq);                         \
      asm volatile("s_waitcnt vmcnt(12)" ::: "memory");                       \
    } else {                                                                  \
      asm volatile("s_waitcnt vmcnt(0)" ::: "memory");                        \
    }                                                                         \
    __builtin_amdgcn_s_barrier();                                             \
    __builtin_amdgcn_sched_barrier(0);                                        \
    const __hip_bfloat16* as_ = As[s_];                                       \
    bf16x8 af[4][2];                                                          \
    _Pragma("unroll")                                                         \
    for (int mb = 0; mb < 4; ++mb) {                                          \
      const int row = wr * 64 + mb * 16 + lrow;                               \
      af[mb][0] = *reinterpret_cast<const bf16x8*>(                           \
          &as_[(row * 8 + ((0 + lq) ^ lx)) * 8]);                             \
      af[mb][1] = *reinterpret_cast<const bf16x8*>(                           \
          &as_[(row * 8 + ((4 + lq) ^ lx)) * 8]);                             \
    }                                                                         \
    _Pragma("unroll")                                                         \
    for (int mb = 0; mb < 4; ++mb)                                            \
      _Pragma("unroll")                                                       \
      for (int nb = 0; nb < 4; ++nb) {                                        \
        acc[mb][nb] = __builtin_amdgcn_mfma_f32_16x16x32_bf16(                \
            af[mb][0], bCur[nb][0], acc[mb][nb], 0, 0, 0);                    \
        acc[mb][nb] = __builtin_amdgcn_mfma_f32_16x16x32_bf16(                \
            af[mb][1], bCur[nb][1], acc[mb][nb], 0, 0, 0);                    \
      }                                                                       \
    __builtin_amdgcn_sched_barrier(0);                                        \
    __builtin_amdgcn_s_barrier();                                             \
  }

  for (int kt = 0; kt < nt; kt += 2) {
    BODY(kt,     0, bE, bO)
    BODY(kt + 1, 1, bO, bE)
  }
#undef BODY
#undef STAGE_A

  // ---- epilogue: C/D layout col=lane&15, row=(lane>>4)*4+j ----
  if (EPI == 0) {
    __hip_bfloat16* out = (__hip_bfloat16*)outbase + (size_t)b * Mdim * Ndim;
#pragma unroll
    for (int mb = 0; mb < 4; ++mb) {
      const int row = r0 + wr * 64 + mb * 16 + lq * 4;
#pragma unroll
      for (int nb = 0; nb < 4; ++nb) {
        const int col = n0 + wc * 64 + nb * 16 + lrow;
        const float bv = bias[col];
#pragma unroll
        for (int j = 0; j < 4; ++j) {
          float g = gelu_fast(acc[mb][nb][j] + bv);
          out[(size_t)(row + j) * Ndim + col] = __float2bfloat16(g);
        }
      }
    }
  } else {
    float* out = (float*)outbase + (size_t)b * Mdim * Ndim;
#pragma unroll
    for (int mb = 0; mb < 4; ++mb) {
      const int row = r0 + wr * 64 + mb * 16 + lq * 4;
#pragma unroll
      for (int nb = 0; nb < 4; ++nb) {
        const int col = n0 + wc * 64 + nb * 16 + lrow;
        const float bv = bias[col];
#pragma unroll
        for (int j = 0; j < 4; ++j)
          out[(size_t)(row + j) * Ndim + col] = acc[mb][nb][j] + bv;
      }
    }
  }
}

// ---------------------------------------------------------------------------
// 4b) GEMM2 — R6's proven gemm_db2 (BM=BN=128, BK=64), unchanged (control).
// ---------------------------------------------------------------------------
template <int EPI>
__global__ __launch_bounds__(256, 2) void gemm_db2(
    const __hip_bfloat16* __restrict__ Abase,
    const __hip_bfloat16* __restrict__ Btbase,
    const float* __restrict__ biasbase,
    void* __restrict__ outbase,
    const int* __restrict__ route,
    int Mdim, int Ndim, int Kdim, int tilesX) {
  const int bid  = blockIdx.x;
  const int b    = bid & 7;
  const int tile = bid >> 3;
  const int bx   = tile % tilesX;
  const int by   = tile / tilesX;
  const int m = route[b];
  const __hip_bfloat16* A  = Abase  + (size_t)b * Mdim * Kdim;
  const __hip_bfloat16* Bt = Btbase + (size_t)m * Ndim * Kdim;
  const float* bias = biasbase + (size_t)m * Ndim;
  const int r0 = bx * 128;
  const int n0 = by * 128;

  __shared__ alignas(16) __hip_bfloat16 As[2][128 * 64];
  __shared__ alignas(16) __hip_bfloat16 Bs[2][128 * 64];

  const int t = threadIdx.x;
  const int w = t >> 6, l = t & 63;
  const int wr = w >> 1, wc = w & 1;

  const int srow = t >> 3;
  const int scol = (t & 7) ^ ((t >> 3) & 7);

#define STAGE(s_, k0)                                                         \
  { _Pragma("unroll")                                                         \
    for (int i = 0; i < 4; ++i)                                               \
      async_copy16(A + (size_t)(r0 + i * 32 + srow) * Kdim + (k0) + scol * 8, \
                   &As[s_][(i * 256 + t) * 8]);                               \
    _Pragma("unroll")                                                         \
    for (int i = 0; i < 4; ++i)                                               \
      async_copy16(Bt + (size_t)(n0 + i * 32 + srow) * Kdim + (k0) + scol * 8,\
                   &Bs[s_][(i * 256 + t) * 8]); }

  const int lrow = l & 15, lq = l >> 4, lx = l & 7;
  f32x4 acc[4][4] = {};
  const int nt = Kdim >> 6;

  STAGE(0, 0)

  for (int kt = 0; kt < nt; ++kt) {
    const int s = kt & 1;
    if (kt + 1 < nt) {
      STAGE(s ^ 1, (kt + 1) * 64)
      asm volatile("s_waitcnt vmcnt(8)" ::: "memory");
    } else {
      asm volatile("s_waitcnt vmcnt(0)" ::: "memory");
    }
    __builtin_amdgcn_s_barrier();
    __builtin_amdgcn_sched_barrier(0);

    const __hip_bfloat16* as_ = As[s];
    const __hip_bfloat16* bs_ = Bs[s];
    bf16x8 af[4][2], bfr[4][2];
#pragma unroll
    for (int mb = 0; mb < 4; ++mb) {
      const int row = wr * 64 + mb * 16 + lrow;
      af[mb][0] = *reinterpret_cast<const bf16x8*>(&as_[(row * 8 + ((0 + lq) ^ lx)) * 8]);
      af[mb][1] = *reinterpret_cast<const bf16x8*>(&as_[(row * 8 + ((4 + lq) ^ lx)) * 8]);
    }
#pragma unroll
    for (int nb = 0; nb < 4; ++nb) {
      const int row = wc * 64 + nb * 16 + lrow;
      bfr[nb][0] = *reinterpret_cast<const bf16x8*>(&bs_[(row * 8 + ((0 + lq) ^ lx)) * 8]);
      bfr[nb][1] = *reinterpret_cast<const bf16x8*>(&bs_[(row * 8 + ((4 + lq) ^ lx)) * 8]);
    }
#pragma unroll
    for (int mb = 0; mb < 4; ++mb)
#pragma unroll
      for (int nb = 0; nb < 4; ++nb) {
        acc[mb][nb] = __builtin_amdgcn_mfma_f32_16x16x32_bf16(
            af[mb][0], bfr[nb][0], acc[mb][nb], 0, 0, 0);
        acc[mb][nb] = __builtin_amdgcn_mfma_f32_16x16x32_bf16(
            af[mb][1], bfr[nb][1], acc[mb][nb], 0, 0, 0);
      }

    __builtin_amdgcn_sched_barrier(0);
    __builtin_amdgcn_s_barrier();
  }
#undef STAGE

  if (EPI == 0) {
    __hip_bfloat16* out = (__hip_bfloat16*)outbase + (size_t)b * Mdim * Ndim;
#pragma unroll
    for (int mb = 0; mb < 4; ++mb) {
      const int row = r0 + wr * 64 + mb * 16 + lq * 4;
#pragma unroll
      for (int nb = 0; nb < 4; ++nb) {
        const int col = n0 + wc * 64 + nb * 16 + lrow;
        const float bv = bias[col];
#pragma unroll
        for (int j = 0; j < 4; ++j) {
          float g = gelu_fast(acc[mb][nb][j] + bv);
          out[(size_t)(row + j) * Ndim + col] = __float2bfloat16(g);
        }
      }
    }
  } else {
    float* out = (float*)outbase + (size_t)b * Mdim * Ndim;
#pragma unroll
    for (int mb = 0; mb < 4; ++mb) {
      const int row = r0 + wr * 64 + mb * 16 + lq * 4;
#pragma unroll
      for (int nb = 0; nb < 4; ++nb) {
        const int col = n0 + wc * 64 + nb * 16 + lrow;
        const float bv = bias[col];
#pragma unroll
        for (int j = 0; j < 4; ++j)
          out[(size_t)(row + j) * Ndim + col] = acc[mb][nb][j] + bv;
      }
    }
  }
}

// ---------------------------------------------------------------------------
extern "C" void kernel_launch(void* const* d_in, const int* in_sizes, int n_in,
                              void* d_out, int out_size, void* d_ws, size_t ws_size,
                              hipStream_t stream) {
  const float* x      = (const float*)d_in[0];
  const float* cond   = (const float*)d_in[1];
  const int*   route  = (const int*)d_in[2];
  const float* W_cond = (const float*)d_in[3];
  const float* b_cond = (const float*)d_in[4];
  const float* W1     = (const float*)d_in[5];
  const float* b1     = (const float*)d_in[6];
  const float* W2     = (const float*)d_in[7];
  const float* b2     = (const float*)d_in[8];
  float* out = (float*)d_out;

  // workspace layout (bytes)
  const size_t SS_OFF   = 0;
  const size_t XMOD_OFF = 32768;
  const size_t W1T_OFF  = XMOD_OFF + (size_t)BATCH * NTOK * DDIM * 2;
  const size_t W2T_OFF  = W1T_OFF + (size_t)NEXP * DDIM * DFFDIM * 2;
  const size_t H_OFF    = W2T_OFF + (size_t)NEXP * DFFDIM * DDIM * 2;
  const size_t NEED     = H_OFF + (size_t)BATCH * NTOK * DFFDIM * 2;
  if (ws_size < NEED) return;

  char* ws = (char*)d_ws;
  float* ss            = (float*)(ws + SS_OFF);
  __hip_bfloat16* xmod = (__hip_bfloat16*)(ws + XMOD_OFF);
  __hip_bfloat16* w1t  = (__hip_bfloat16*)(ws + W1T_OFF);
  __hip_bfloat16* w2t  = (__hip_bfloat16*)(ws + W2T_OFF);
  __hip_bfloat16* h    = (__hip_bfloat16*)(ws + H_OFF);

  // 1) cond modulation
  mod_kernel<<<dim3(2 * DDIM / 64, BATCH), 256, 0, stream>>>(cond, route, W_cond, b_cond, ss);

  // 2) FiLM -> bf16
  {
    const size_t groups = (size_t)BATCH * NTOK * DDIM / 4;
    film_kernel<<<(unsigned)(groups / 256), 256, 0, stream>>>(x, ss, xmod);
  }

  // 3) weight transpose+convert (routed experts only)
  transpose_cvt<<<dim3(DFFDIM / 32, DDIM / 32, NEXP), dim3(32, 8), 0, stream>>>(W1, w1t, DDIM, DFFDIM, route);
  transpose_cvt<<<dim3(DDIM / 32, DFFDIM / 32, NEXP), dim3(32, 8), 0, stream>>>(W2, w2t, DFFDIM, DDIM, route);

  // 4) GEMM1 (B-direct experiment): h = gelu(xmod @ W1 + b1), grid 2048
  gemm_bd<0><<<(NTOK / 128) * (DFFDIM / 128) * BATCH, 256, 0, stream>>>(
      xmod, w1t, b1, h, route, NTOK, DFFDIM, DDIM, NTOK / 128);

  // 5) GEMM2 (R6 control): out = h @ W2 + b2, grid 512
  gemm_db2<1><<<(NTOK / 128) * (DDIM / 128) * BATCH, 256, 0, stream>>>(
      h, w2t, b2, out, route, NTOK, DDIM, DFFDIM, NTOK / 128);
}

// Round 9
// 131.150 us; speedup vs baseline: 1.3085x; 1.2484x over previous
//
#include <hip/hip_runtime.h>
#include <hip/hip_bf16.h>
#include <cstdint>
#include <cstddef>

// Problem dims (fixed by the reference)
#define NEXP   8
#define BATCH  8
#define NTOK   2048
#define DDIM   512
#define DFFDIM 2048
#define DCOND  512

typedef float  f32x4  __attribute__((ext_vector_type(4)));
typedef __bf16 bf16x8 __attribute__((ext_vector_type(8)));

using as1_cvoid = __attribute__((address_space(1))) const void;
using as3_void  = __attribute__((address_space(3))) void;

__device__ __forceinline__ void async_copy16(const void* g, void* l) {
  __builtin_amdgcn_global_load_lds((as1_cvoid*)g, (as3_void*)l, 16, 0, 0);
}

__device__ __forceinline__ unsigned short f2bf_bits(float f) {
  __hip_bfloat16 h = __float2bfloat16(f);
  return *reinterpret_cast<unsigned short*>(&h);
}

// fast tanh-approx gelu: 0.5v(1+tanh(z)) == v * sigmoid(2z)
__device__ __forceinline__ float gelu_fast(float v) {
  float y = v * fmaf(0.0713548162726f, v * v, 1.5957691216057f);
  float e = exp2f(-1.44269504089f * y);
  return v * __builtin_amdgcn_rcpf(1.0f + e);
}

// ---------------------------------------------------------------------------
// 1) scale/shift = cond[b] @ W_cond[route[b]] + b_cond[route[b]] -> ss[B][1024]
// ---------------------------------------------------------------------------
__global__ void mod_kernel(const float* __restrict__ cond,
                           const int* __restrict__ route,
                           const float* __restrict__ W_cond,
                           const float* __restrict__ b_cond,
                           float* __restrict__ ss) {
  const int b = blockIdx.y;
  const int m = route[b];
  const int tj = threadIdx.x & 63;
  const int cq = threadIdx.x >> 6;            // 0..3
  const int j = blockIdx.x * 64 + tj;
  const float* wc = W_cond + (size_t)m * DCOND * (2 * DDIM);
  const float* cb = cond + (size_t)b * DCOND;
  float acc = 0.f;
#pragma unroll 4
  for (int c = cq * 128; c < cq * 128 + 128; ++c)
    acc += cb[c] * wc[(size_t)c * (2 * DDIM) + j];
  __shared__ float red[4][64];
  red[cq][tj] = acc;
  __syncthreads();
  if (cq == 0) {
    float v = red[0][tj] + red[1][tj] + red[2][tj] + red[3][tj];
    ss[(size_t)b * (2 * DDIM) + j] = v + b_cond[(size_t)m * (2 * DDIM) + j];
  }
}

// ---------------------------------------------------------------------------
// 2) x_mod = bf16( x * (1+scale) + shift )   [B][N][D] bf16
// ---------------------------------------------------------------------------
__global__ void film_kernel(const float* __restrict__ x,
                            const float* __restrict__ ss,
                            __hip_bfloat16* __restrict__ xmod) {
  const size_t idx = (size_t)blockIdx.x * blockDim.x + threadIdx.x;
  const int d4 = (int)(idx & (DDIM / 4 - 1));
  const int b  = (int)(idx >> 18);
  const float4 xv = reinterpret_cast<const float4*>(x)[idx];
  const float4 sc = reinterpret_cast<const float4*>(ss + (size_t)b * 1024)[d4];
  const float4 sh = reinterpret_cast<const float4*>(ss + (size_t)b * 1024 + DDIM)[d4];
  float r0 = xv.x * (1.f + sc.x) + sh.x;
  float r1 = xv.y * (1.f + sc.y) + sh.y;
  float r2 = xv.z * (1.f + sc.z) + sh.z;
  float r3 = xv.w * (1.f + sc.w) + sh.w;
  ushort4 ov;
  ov.x = f2bf_bits(r0); ov.y = f2bf_bits(r1);
  ov.z = f2bf_bits(r2); ov.w = f2bf_bits(r3);
  reinterpret_cast<ushort4*>(xmod)[idx] = ov;
}

// ---------------------------------------------------------------------------
// 3) transpose + f32->bf16:  in [M][L][R] f32  ->  out [M][R][L] bf16
// ---------------------------------------------------------------------------
__global__ void transpose_cvt(const float* __restrict__ in,
                              __hip_bfloat16* __restrict__ outp,
                              int L, int R,
                              const int* __restrict__ route) {
  const int mi = blockIdx.z;
  bool used = false;
#pragma unroll
  for (int b = 0; b < BATCH; ++b) used |= (route[b] == mi);
  if (!used) return;

  __shared__ float tile[32][33];
  const float* inm = in + (size_t)mi * L * R;
  __hip_bfloat16* outm = outp + (size_t)mi * L * R;
  const int r0 = blockIdx.x * 32, l0 = blockIdx.y * 32;
  const int tx = threadIdx.x, ty = threadIdx.y;
#pragma unroll
  for (int i = 0; i < 32; i += 8)
    tile[ty + i][tx] = inm[(size_t)(l0 + ty + i) * R + r0 + tx];
  __syncthreads();
#pragma unroll
  for (int i = 0; i < 32; i += 8)
    outm[(size_t)(r0 + ty + i) * L + l0 + tx] = __float2bfloat16(tile[tx][ty + i]);
}

// ---------------------------------------------------------------------------
// 4a) 8-PHASE GEMM (m201 port): BM=BN=256, BK=64, 512 threads = 8 waves
//     (2M x 4N), wave-tile 128x64, acc 8x4 f32x4.  LDS 128 KB:
//     As[2buf][2half][128x64], Bs likewise (half = 128 rows).
//     Per K-tile: 4 phases, each = {ds-read subtile, stage 1 half-tile,
//     barrier, 16 MFMA (one C-quadrant x K=64) in setprio(1), barrier}.
//     Stage->half map (ledger-verified):
//       ph0: A1(k+1)  [opposite buf - always safe]
//       ph1: B1(k+1)  [opposite buf]
//       ph2: B0(k+2)  [current buf; all B reads done by ph1-end barrier]
//       ph3: A0(k+2)  [current buf; all A reads done by ph2-end barrier]
//     Entry wait vmcnt(4): newest 2 half-tiles (B0/A0 of k+1..k+2) stay in
//     flight; retires A1(k),B1(k) (staged 3-4 stages ago) + everything older.
//     Last tile: vmcnt(0).  Swizzle: R6-verified (LDS(r,c)=global(r,c^(r&7)),
//     linear gload_lds dest + inverse-swizzled source + swizzled ds_read).
// ---------------------------------------------------------------------------
template <int EPI>
__global__ __launch_bounds__(512, 1) void gemm_8ph(
    const __hip_bfloat16* __restrict__ A,
    const __hip_bfloat16* __restrict__ Btb,
    const float* __restrict__ biasbase,
    void* __restrict__ outbase,
    const int* __restrict__ route,
    int Mdim, int Ndim, int Kdim, int tilesX) {
  const int bid  = blockIdx.x;
  const int b    = bid & 7;            // batch -> XCD
  const int tile = bid >> 3;
  const int bx   = tile % tilesX;
  const int by   = tile / tilesX;
  const int m = route[b];
  const __hip_bfloat16* Ab = A   + (size_t)b * Mdim * Kdim;
  const __hip_bfloat16* Bt = Btb + (size_t)m * Ndim * Kdim;
  const float* bias = biasbase + (size_t)m * Ndim;
  const int r0 = bx * 256;
  const int n0 = by * 256;

  __shared__ alignas(16) __hip_bfloat16 As[2][2][128 * 64];  // 64 KB
  __shared__ alignas(16) __hip_bfloat16 Bs[2][2][128 * 64];  // 64 KB

  const int t = threadIdx.x;
  const int w = t >> 6, l = t & 63;
  const int wm = w >> 2;               // 0..1  (M half, 128 rows)
  const int wn = w & 3;                // 0..3  (N quarter, 64 cols)

  // staging: 512 threads x 2 loads cover one 128x64 half-tile (16 KB).
  const int srow = t >> 3;                     // 0..63
  const int scol = (t & 7) ^ ((t >> 3) & 7);   // inverse-swizzled 16B chunk

#define STAGE_AH(sb, ha, k0)                                                  \
  { async_copy16(Ab + (size_t)(r0 + (ha) * 128 + srow) * Kdim + (k0) + scol * 8, \
                 &As[sb][ha][(size_t)t * 8]);                                 \
    async_copy16(Ab + (size_t)(r0 + (ha) * 128 + 64 + srow) * Kdim + (k0) + scol * 8, \
                 &As[sb][ha][(size_t)(512 + t) * 8]); }
#define STAGE_BH(sb, hb, k0)                                                  \
  { async_copy16(Bt + (size_t)(n0 + (hb) * 128 + srow) * Kdim + (k0) + scol * 8, \
                 &Bs[sb][hb][(size_t)t * 8]);                                 \
    async_copy16(Bt + (size_t)(n0 + (hb) * 128 + 64 + srow) * Kdim + (k0) + scol * 8, \
                 &Bs[sb][hb][(size_t)(512 + t) * 8]); }

  const int lrow = l & 15, lq = l >> 4, lx = l & 7;

#define LOAD_A(mh)                                                            \
  { _Pragma("unroll")                                                         \
    for (int i = 0; i < 4; ++i) {                                             \
      const int row = ((mh) * 4 + i) * 16 + lrow;                             \
      aF[i][0] = *reinterpret_cast<const bf16x8*>(&aH[(row * 8 + ((0 + lq) ^ lx)) * 8]); \
      aF[i][1] = *reinterpret_cast<const bf16x8*>(&aH[(row * 8 + ((4 + lq) ^ lx)) * 8]); \
    } }
#define LOAD_B(nh)                                                            \
  { _Pragma("unroll")                                                         \
    for (int j = 0; j < 2; ++j) {                                             \
      const int row = (wn & 1) * 64 + ((nh) * 2 + j) * 16 + lrow;             \
      bF[nh][j][0] = *reinterpret_cast<const bf16x8*>(&bH[(row * 8 + ((0 + lq) ^ lx)) * 8]); \
      bF[nh][j][1] = *reinterpret_cast<const bf16x8*>(&bH[(row * 8 + ((4 + lq) ^ lx)) * 8]); \
    } }
#define MFMA_Q(mh, nh)                                                        \
  { __builtin_amdgcn_s_setprio(1);                                            \
    _Pragma("unroll")                                                         \
    for (int i = 0; i < 4; ++i)                                               \
      _Pragma("unroll")                                                       \
      for (int j = 0; j < 2; ++j) {                                           \
        acc[(mh) * 4 + i][(nh) * 2 + j] = __builtin_amdgcn_mfma_f32_16x16x32_bf16( \
            aF[i][0], bF[nh][j][0], acc[(mh) * 4 + i][(nh) * 2 + j], 0, 0, 0);\
        acc[(mh) * 4 + i][(nh) * 2 + j] = __builtin_amdgcn_mfma_f32_16x16x32_bf16( \
            aF[i][1], bF[nh][j][1], acc[(mh) * 4 + i][(nh) * 2 + j], 0, 0, 0);\
      }                                                                       \
    __builtin_amdgcn_s_setprio(0); }
#define BARSCHED  { __builtin_amdgcn_s_barrier(); __builtin_amdgcn_sched_barrier(0); }

  f32x4 acc[8][4] = {};
  const int nt = Kdim >> 6;

  // prologue: 6 half-tiles, stream order matches steady-state ledger
  STAGE_BH(0, 0, 0)
  STAGE_AH(0, 0, 0)
  STAGE_AH(0, 1, 0)
  STAGE_BH(0, 1, 0)
  if (nt > 1) { STAGE_BH(1, 0, 64) STAGE_AH(1, 0, 64) }

  for (int kt = 0; kt < nt; ++kt) {
    const int s = kt & 1;
    if (kt == nt - 1) { asm volatile("s_waitcnt vmcnt(0)" ::: "memory"); }
    else              { asm volatile("s_waitcnt vmcnt(4)" ::: "memory"); }
    BARSCHED

    const __hip_bfloat16* aH = As[s][wm];
    const __hip_bfloat16* bH = Bs[s][wn >> 1];
    bf16x8 aF[4][2], bF[2][2][2];

    // phase 0: read A(mh0)+B(nh0); stage A1(kt+1); C-quadrant (0,0)
    LOAD_A(0)
    LOAD_B(0)
    if (kt + 1 < nt) STAGE_AH(s ^ 1, 1, (kt + 1) * 64)
    BARSCHED
    MFMA_Q(0, 0)
    BARSCHED

    // phase 1: read B(nh1); stage B1(kt+1); quadrant (0,1)
    LOAD_B(1)
    if (kt + 1 < nt) STAGE_BH(s ^ 1, 1, (kt + 1) * 64)
    BARSCHED
    MFMA_Q(0, 1)
    BARSCHED

    // phase 2: read A(mh1); stage B0(kt+2); quadrant (1,0)
    LOAD_A(1)
    if (kt + 2 < nt) STAGE_BH(s, 0, (kt + 2) * 64)
    BARSCHED
    MFMA_Q(1, 0)
    BARSCHED

    // phase 3: stage A0(kt+2); quadrant (1,1); loop-top vmcnt+barrier follows
    if (kt + 2 < nt) STAGE_AH(s, 0, (kt + 2) * 64)
    MFMA_Q(1, 1)
  }
#undef STAGE_AH
#undef STAGE_BH
#undef LOAD_A
#undef LOAD_B
#undef MFMA_Q
#undef BARSCHED

  // ---- epilogue: C/D layout col=lane&15, row=(lane>>4)*4+j ----
  if (EPI == 0) {
    __hip_bfloat16* out = (__hip_bfloat16*)outbase + (size_t)b * Mdim * Ndim;
#pragma unroll
    for (int mb = 0; mb < 8; ++mb) {
      const int row = r0 + wm * 128 + mb * 16 + lq * 4;
#pragma unroll
      for (int nb = 0; nb < 4; ++nb) {
        const int col = n0 + wn * 64 + nb * 16 + lrow;
        const float bv = bias[col];
#pragma unroll
        for (int j = 0; j < 4; ++j) {
          float g = gelu_fast(acc[mb][nb][j] + bv);
          out[(size_t)(row + j) * Ndim + col] = __float2bfloat16(g);
        }
      }
    }
  } else {
    float* out = (float*)outbase + (size_t)b * Mdim * Ndim;
#pragma unroll
    for (int mb = 0; mb < 8; ++mb) {
      const int row = r0 + wm * 128 + mb * 16 + lq * 4;
#pragma unroll
      for (int nb = 0; nb < 4; ++nb) {
        const int col = n0 + wn * 64 + nb * 16 + lrow;
        const float bv = bias[col];
#pragma unroll
        for (int j = 0; j < 4; ++j)
          out[(size_t)(row + j) * Ndim + col] = acc[mb][nb][j] + bv;
      }
    }
  }
}

// ---------------------------------------------------------------------------
// 4b) GEMM2 — R6's proven gemm_db2 (BM=BN=128, BK=64), unchanged (control).
// ---------------------------------------------------------------------------
template <int EPI>
__global__ __launch_bounds__(256, 2) void gemm_db2(
    const __hip_bfloat16* __restrict__ Abase,
    const __hip_bfloat16* __restrict__ Btbase,
    const float* __restrict__ biasbase,
    void* __restrict__ outbase,
    const int* __restrict__ route,
    int Mdim, int Ndim, int Kdim, int tilesX) {
  const int bid  = blockIdx.x;
  const int b    = bid & 7;
  const int tile = bid >> 3;
  const int bx   = tile % tilesX;
  const int by   = tile / tilesX;
  const int m = route[b];
  const __hip_bfloat16* A  = Abase  + (size_t)b * Mdim * Kdim;
  const __hip_bfloat16* Bt = Btbase + (size_t)m * Ndim * Kdim;
  const float* bias = biasbase + (size_t)m * Ndim;
  const int r0 = bx * 128;
  const int n0 = by * 128;

  __shared__ alignas(16) __hip_bfloat16 As[2][128 * 64];
  __shared__ alignas(16) __hip_bfloat16 Bs[2][128 * 64];

  const int t = threadIdx.x;
  const int w = t >> 6, l = t & 63;
  const int wr = w >> 1, wc = w & 1;

  const int srow = t >> 3;
  const int scol = (t & 7) ^ ((t >> 3) & 7);

#define STAGE(s_, k0)                                                         \
  { _Pragma("unroll")                                                         \
    for (int i = 0; i < 4; ++i)                                               \
      async_copy16(A + (size_t)(r0 + i * 32 + srow) * Kdim + (k0) + scol * 8, \
                   &As[s_][(i * 256 + t) * 8]);                               \
    _Pragma("unroll")                                                         \
    for (int i = 0; i < 4; ++i)                                               \
      async_copy16(Bt + (size_t)(n0 + i * 32 + srow) * Kdim + (k0) + scol * 8,\
                   &Bs[s_][(i * 256 + t) * 8]); }

  const int lrow = l & 15, lq = l >> 4, lx = l & 7;
  f32x4 acc[4][4] = {};
  const int nt = Kdim >> 6;

  STAGE(0, 0)

  for (int kt = 0; kt < nt; ++kt) {
    const int s = kt & 1;
    if (kt + 1 < nt) {
      STAGE(s ^ 1, (kt + 1) * 64)
      asm volatile("s_waitcnt vmcnt(8)" ::: "memory");
    } else {
      asm volatile("s_waitcnt vmcnt(0)" ::: "memory");
    }
    __builtin_amdgcn_s_barrier();
    __builtin_amdgcn_sched_barrier(0);

    const __hip_bfloat16* as_ = As[s];
    const __hip_bfloat16* bs_ = Bs[s];
    bf16x8 af[4][2], bfr[4][2];
#pragma unroll
    for (int mb = 0; mb < 4; ++mb) {
      const int row = wr * 64 + mb * 16 + lrow;
      af[mb][0] = *reinterpret_cast<const bf16x8*>(&as_[(row * 8 + ((0 + lq) ^ lx)) * 8]);
      af[mb][1] = *reinterpret_cast<const bf16x8*>(&as_[(row * 8 + ((4 + lq) ^ lx)) * 8]);
    }
#pragma unroll
    for (int nb = 0; nb < 4; ++nb) {
      const int row = wc * 64 + nb * 16 + lrow;
      bfr[nb][0] = *reinterpret_cast<const bf16x8*>(&bs_[(row * 8 + ((0 + lq) ^ lx)) * 8]);
      bfr[nb][1] = *reinterpret_cast<const bf16x8*>(&bs_[(row * 8 + ((4 + lq) ^ lx)) * 8]);
    }
#pragma unroll
    for (int mb = 0; mb < 4; ++mb)
#pragma unroll
      for (int nb = 0; nb < 4; ++nb) {
        acc[mb][nb] = __builtin_amdgcn_mfma_f32_16x16x32_bf16(
            af[mb][0], bfr[nb][0], acc[mb][nb], 0, 0, 0);
        acc[mb][nb] = __builtin_amdgcn_mfma_f32_16x16x32_bf16(
            af[mb][1], bfr[nb][1], acc[mb][nb], 0, 0, 0);
      }

    __builtin_amdgcn_sched_barrier(0);
    __builtin_amdgcn_s_barrier();
  }
#undef STAGE

  if (EPI == 0) {
    __hip_bfloat16* out = (__hip_bfloat16*)outbase + (size_t)b * Mdim * Ndim;
#pragma unroll
    for (int mb = 0; mb < 4; ++mb) {
      const int row = r0 + wr * 64 + mb * 16 + lq * 4;
#pragma unroll
      for (int nb = 0; nb < 4; ++nb) {
        const int col = n0 + wc * 64 + nb * 16 + lrow;
        const float bv = bias[col];
#pragma unroll
        for (int j = 0; j < 4; ++j) {
          float g = gelu_fast(acc[mb][nb][j] + bv);
          out[(size_t)(row + j) * Ndim + col] = __float2bfloat16(g);
        }
      }
    }
  } else {
    float* out = (float*)outbase + (size_t)b * Mdim * Ndim;
#pragma unroll
    for (int mb = 0; mb < 4; ++mb) {
      const int row = r0 + wr * 64 + mb * 16 + lq * 4;
#pragma unroll
      for (int nb = 0; nb < 4; ++nb) {
        const int col = n0 + wc * 64 + nb * 16 + lrow;
        const float bv = bias[col];
#pragma unroll
        for (int j = 0; j < 4; ++j)
          out[(size_t)(row + j) * Ndim + col] = acc[mb][nb][j] + bv;
      }
    }
  }
}

// ---------------------------------------------------------------------------
extern "C" void kernel_launch(void* const* d_in, const int* in_sizes, int n_in,
                              void* d_out, int out_size, void* d_ws, size_t ws_size,
                              hipStream_t stream) {
  const float* x      = (const float*)d_in[0];
  const float* cond   = (const float*)d_in[1];
  const int*   route  = (const int*)d_in[2];
  const float* W_cond = (const float*)d_in[3];
  const float* b_cond = (const float*)d_in[4];
  const float* W1     = (const float*)d_in[5];
  const float* b1     = (const float*)d_in[6];
  const float* W2     = (const float*)d_in[7];
  const float* b2     = (const float*)d_in[8];
  float* out = (float*)d_out;

  // workspace layout (bytes)
  const size_t SS_OFF   = 0;
  const size_t XMOD_OFF = 32768;
  const size_t W1T_OFF  = XMOD_OFF + (size_t)BATCH * NTOK * DDIM * 2;
  const size_t W2T_OFF  = W1T_OFF + (size_t)NEXP * DDIM * DFFDIM * 2;
  const size_t H_OFF    = W2T_OFF + (size_t)NEXP * DFFDIM * DDIM * 2;
  const size_t NEED     = H_OFF + (size_t)BATCH * NTOK * DFFDIM * 2;
  if (ws_size < NEED) return;

  char* ws = (char*)d_ws;
  float* ss            = (float*)(ws + SS_OFF);
  __hip_bfloat16* xmod = (__hip_bfloat16*)(ws + XMOD_OFF);
  __hip_bfloat16* w1t  = (__hip_bfloat16*)(ws + W1T_OFF);
  __hip_bfloat16* w2t  = (__hip_bfloat16*)(ws + W2T_OFF);
  __hip_bfloat16* h    = (__hip_bfloat16*)(ws + H_OFF);

  // 1) cond modulation
  mod_kernel<<<dim3(2 * DDIM / 64, BATCH), 256, 0, stream>>>(cond, route, W_cond, b_cond, ss);

  // 2) FiLM -> bf16
  {
    const size_t groups = (size_t)BATCH * NTOK * DDIM / 4;
    film_kernel<<<(unsigned)(groups / 256), 256, 0, stream>>>(x, ss, xmod);
  }

  // 3) weight transpose+convert (routed experts only)
  transpose_cvt<<<dim3(DFFDIM / 32, DDIM / 32, NEXP), dim3(32, 8), 0, stream>>>(W1, w1t, DDIM, DFFDIM, route);
  transpose_cvt<<<dim3(DDIM / 32, DFFDIM / 32, NEXP), dim3(32, 8), 0, stream>>>(W2, w2t, DFFDIM, DDIM, route);

  // 4) GEMM1 (8-phase): h = gelu(xmod @ W1 + b1), grid 8*8*8 = 512 blocks
  gemm_8ph<0><<<(NTOK / 256) * (DFFDIM / 256) * BATCH, 512, 0, stream>>>(
      xmod, w1t, b1, h, route, NTOK, DFFDIM, DDIM, NTOK / 256);

  // 5) GEMM2 (R6 control): out = h @ W2 + b2, grid 512 blocks
  gemm_db2<1><<<(NTOK / 128) * (DDIM / 128) * BATCH, 256, 0, stream>>>(
      h, w2t, b2, out, route, NTOK, DDIM, DFFDIM, NTOK / 128);
}